// Round 10
// baseline (177.885 us; speedup 1.0000x reference)
//
#include <hip/hip_runtime.h>
#include <hip/hip_bf16.h>

#define B_    8
#define N_    2048
#define FIN_  256
#define FOUT_ 128
#define NROWS (B_*N_)

typedef __attribute__((ext_vector_type(8))) short short8;
typedef __attribute__((ext_vector_type(4))) float f32x4;

__device__ __forceinline__ float bf2f(unsigned short u) {
  return __uint_as_float(((unsigned int)u) << 16);
}
__device__ __forceinline__ unsigned short f2bf(float f) {
  unsigned int u = __float_as_uint(f);
  u += 0x7FFFu + ((u >> 16) & 1u);   // RNE
  return (unsigned short)(u >> 16);
}
__device__ __forceinline__ float ldin(const void* p, size_t idx, int isbf) {
  if (isbf) return bf2f(((const unsigned short*)p)[idx]);
  return ((const float*)p)[idx];
}
__device__ __forceinline__ unsigned pk2bf(float a, float b) {
  return (unsigned)f2bf(a) | ((unsigned)f2bf(b) << 16);   // low = a (RNE)
}
// native exp2 (single v_exp_f32); fallback keeps exact same math via e^(x*ln2)
__device__ __forceinline__ float ex2(float x) {
#if __has_builtin(__builtin_amdgcn_exp2f)
  return __builtin_amdgcn_exp2f(x);
#else
  return __expf(x * 0.69314718056f);
#endif
}
// monotone float<->uint encoding for atomicMax float-max (all finite enc > 0)
__device__ __forceinline__ unsigned encf(float f) {
  unsigned u = __float_as_uint(f);
  return (u & 0x80000000u) ? ~u : (u | 0x80000000u);
}
__device__ __forceinline__ float decf(unsigned k) {
  return (k & 0x80000000u) ? __uint_as_float(k ^ 0x80000000u) : __uint_as_float(~k);
}
// per-block dtype self-detect (deterministic across blocks)
__device__ __forceinline__ int detect_bf(const void* x, int* cnt) {
  const unsigned short* u = (const unsigned short*)x;
  int c = 0;
  for (int i = threadIdx.x; i < 8192; i += 256) {
    unsigned short v = u[i];
    int e = (v >> 7) & 0xFF;
    if ((e >= 110 && e <= 145) || (v & 0x7FFF) == 0) c++;
  }
  cnt[threadIdx.x] = c;
  __syncthreads();
  for (int s = 128; s > 0; s >>= 1) {
    if (threadIdx.x < s) cnt[threadIdx.x] += cnt[threadIdx.x + s];
    __syncthreads();
  }
  return cnt[0] > 7373;   // 0.9 * 8192
}

// ---------- kernel 0: self-detect; blocks 0..127: WT; block 128: wa, flag,
//            MdstE init ----------
__global__ __launch_bounds__(256)
void k_prep(const void* __restrict__ x, const void* __restrict__ W,
            const void* __restrict__ a,
            unsigned short* __restrict__ WT, float* __restrict__ wa,
            int* __restrict__ flag, unsigned* __restrict__ MdstE) {
  __shared__ int cnt[256];
  const int isbf = detect_bf(x, cnt);
  if (blockIdx.x < 128) {
    int f = blockIdx.x, k = threadIdx.x;
    WT[f * 256 + k] = f2bf(ldin(W, (size_t)k * 128 + f, isbf));
  } else {
    __shared__ float as_s[256];
    int k = threadIdx.x;
    as_s[k] = ldin(a, k, isbf);
    __syncthreads();
    float s = 0.f, d = 0.f;
    for (int f = 0; f < 128; f++) {
      float w = ldin(W, (size_t)k * 128 + f, isbf);
      s += w * as_s[f];
      d += w * as_s[128 + f];
    }
    wa[k] = s;
    wa[256 + k] = d;
    if (k == 0) *flag = isbf;
    if (k < 8) MdstE[k * 32] = 0u;     // 0 < enc(f) for all finite f
  }
}

// ---------- kernel 1: h = x@W bf16 MFMA -> hT; fused fsrc/fdst = x@wa;
//            fused per-batch fdst max; cpack = (cx,cy,cz, fdst*log2e).
// hT 16B-half XOR swizzle on bit2 of f (phys_half = logical_half ^
// ((f>>2)&1)); k_attn reads with the matching hsel XOR. ----------
__global__ __launch_bounds__(256)
void k_h(const void* __restrict__ x, const void* __restrict__ coord,
         const unsigned short* __restrict__ WT,
         const float* __restrict__ wa, const int* __restrict__ flag,
         unsigned short* __restrict__ hT, float* __restrict__ fsrc,
         float4* __restrict__ cpack, unsigned* __restrict__ MdstE) {
  __shared__ __align__(16) unsigned short xs[32][264];
  __shared__ float wa_s[512];
  __shared__ float mxs[8];
  const int isbf = *flag;
  const int t    = threadIdx.x;
  const int row0 = blockIdx.x * 32;

  wa_s[t] = wa[t];
  wa_s[256 + t] = wa[256 + t];
  __syncthreads();

  const int c = t & 31;
  float sp[4], dp[4];
  if (isbf) {
    const unsigned short* xu = (const unsigned short*)x;
#pragma unroll
    for (int u = 0; u < 4; u++) {
      int r = u * 8 + (t >> 5);
      short8 sh = *(const short8*)&xu[(size_t)(row0 + r) * FIN_ + c * 8];
      *(short8*)&xs[r][c * 8] = sh;
      float s = 0.f, d = 0.f;
#pragma unroll
      for (int e = 0; e < 8; e++) {
        float xv = bf2f((unsigned short)sh[e]);
        s += xv * wa_s[c * 8 + e];
        d += xv * wa_s[256 + c * 8 + e];
      }
      sp[u] = s; dp[u] = d;
    }
  } else {
    const float* xf = (const float*)x;
#pragma unroll
    for (int u = 0; u < 4; u++) {
      int r = u * 8 + (t >> 5);
      float4 v0 = *(const float4*)&xf[(size_t)(row0 + r) * FIN_ + c * 8];
      float4 v1 = *(const float4*)&xf[(size_t)(row0 + r) * FIN_ + c * 8 + 4];
      float vv[8] = {v0.x, v0.y, v0.z, v0.w, v1.x, v1.y, v1.z, v1.w};
      short8 sh;
      float s = 0.f, d = 0.f;
#pragma unroll
      for (int e = 0; e < 8; e++) {
        sh[e] = (short)f2bf(vv[e]);
        s += vv[e] * wa_s[c * 8 + e];
        d += vv[e] * wa_s[256 + c * 8 + e];
      }
      *(short8*)&xs[r][c * 8] = sh;
      sp[u] = s; dp[u] = d;
    }
  }
#pragma unroll
  for (int off = 16; off >= 1; off >>= 1) {
#pragma unroll
    for (int u = 0; u < 4; u++) {
      sp[u] += __shfl_xor(sp[u], off, 64);
      dp[u] += __shfl_xor(dp[u], off, 64);
    }
  }
  if (c == 0) {
    float lm = -1e30f;
#pragma unroll
    for (int u = 0; u < 4; u++) {
      int r = u * 8 + (t >> 5);
      size_t rg = (size_t)(row0 + r);
      fsrc[rg] = sp[u];
      cpack[rg] = make_float4(ldin(coord, rg * 3 + 0, isbf),
                              ldin(coord, rg * 3 + 1, isbf),
                              ldin(coord, rg * 3 + 2, isbf),
                              dp[u] * 1.44269504f);     // fdst pre-scaled by log2e
      lm = fmaxf(lm, dp[u]);
    }
    mxs[t >> 5] = lm;
  }
  __syncthreads();
  if (t == 0) {
    float m8 = mxs[0];
#pragma unroll
    for (int i = 1; i < 8; i++) m8 = fmaxf(m8, mxs[i]);
    atomicMax(&MdstE[(row0 >> 11) * 32], encf(m8));   // 64 atomics/line, padded
  }

  const int lane = t & 63, w = t >> 6;
  const int m = lane & 15, quad = lane >> 4;
  const int slab = w >> 1, fh = w & 1;

  f32x4 acc[4];
#pragma unroll
  for (int i = 0; i < 4; i++) acc[i] = (f32x4){0.f, 0.f, 0.f, 0.f};

#pragma unroll
  for (int ks = 0; ks < 8; ks++) {
    short8 ah = *(const short8*)&xs[slab * 16 + m][ks * 32 + quad * 8];
#pragma unroll
    for (int ft = 0; ft < 4; ft++) {
      int f = fh * 64 + ft * 16 + m;
      short8 bh = *(const short8*)&WT[(size_t)f * 256 + ks * 32 + quad * 8];
      acc[ft] = __builtin_amdgcn_mfma_f32_16x16x32_bf16(ah, bh, acc[ft], 0, 0, 0);
    }
  }

  size_t n0 = (size_t)blockIdx.x * 2 + slab;
  unsigned short* hblk = hT + n0 * (FOUT_ * 16);
#pragma unroll
  for (int ft = 0; ft < 4; ft++) {
    int f = fh * 64 + ft * 16 + m;
    int jo = (quad * 4) ^ (((f >> 2) & 1) << 3);   // bank-swizzled 16B half
    *(uint2*)&hblk[f * 16 + jo] = make_uint2(
        pk2bf(acc[ft][0], acc[ft][1]), pk2bf(acc[ft][2], acc[ft][3]));
  }
}

// ---------- kernel 2 (r27): r26 + cj from GLOBAL (cjs LDS eliminated) ----
// r26 passed at 132.6us, confirming the LDS-issue model (time tracks LDS
// wave-instr count). Remaining 272 instrs/tile: cjs reads 128 (the largest),
// A 64, B 32, stage-writes 32, phi-writes 16. The cjs array is a bit-exact
// copy of cpack (L1/L2-resident 2KB per tile) broadcast through the
// bottleneck pipe. r27 deletes cjs entirely: each thread loads its 8 cj
// float4s directly from global (8x global_load_dwordx4, L1-hit, identical
// values/indices), issued at the TOP of the iteration and consumed AFTER
// mfma_tile -- MFMA+LDS work plus 4-wave TLP hides the latency (T14).
// LDS instrs/tile 272 -> 144. Roles/phi/MFMA/merge byte-identical to r26.
__global__ __launch_bounds__(1024, 4)
void k_attn(const unsigned short* __restrict__ hT, const float4* __restrict__ cpack,
            const float* __restrict__ fsrc, const unsigned* __restrict__ MdstE,
            const int* __restrict__ flag, void* __restrict__ out) {
  const int isbf = *flag;
  const int tid = threadIdx.x;
  const int b   = blockIdx.x >> 5;
  const int q0  = (blockIdx.x & 31) * 64;

  __shared__ __align__(16) uint4 ldsBu[2][2048];            // 64 KB B panels
  __shared__ __align__(16) unsigned short phi[2][64][136];  // 34 KB
  __shared__ float denomS[64];

  // ---- logit roles (r21/r26 verbatim) ----
  const int qA   = tid >> 4;              // 0..63: logit q row
  const int jseg = tid & 15;              // 8 j's: jseg*8 + 0..7
  const size_t qglb = (size_t)b * N_ + q0 + qA;
  const float4 cq  = cpack[qglb];
  const float  fsq = fsrc[qglb];
  const float  fsqL = fsq * 1.44269504f;
  const float  mBqL = -fmaxf(0.f, fsq + decf(MdstE[b * 32])) * 1.44269504f;
  float ds = 0.f;                         // f32 sum of this thread's bf16 p's

  // ---- mfma roles: 16 waves = 4 fg x 4 js (K-quarter), r26 verbatim ----
  const int lane = tid & 63, w = tid >> 6;
  const int m = lane & 15, quad = lane >> 4;
  const int fg = w & 3, js = w >> 2;
  const int hsel = (quad & 1) ^ ((m >> 2) & 1);   // undo producer swizzle

  f32x4 acc[4][2];                        // [q-tile][f-subtile]
#pragma unroll
  for (int i = 0; i < 4; i++)
#pragma unroll
    for (int j = 0; j < 2; j++) acc[i][j] = (f32x4){0.f, 0.f, 0.f, 0.f};

  const unsigned short* hTb = hT + (size_t)b * (N_ * FOUT_);
  const uint4* gB = (const uint4*)hTb;            // 2048 uint4 per 128-j tile
  const float4* cpb = cpack + (size_t)b * N_;
  const float4* cjg = cpb + jseg * 8;             // this thread's j-window base

  // logits on register-resident cj (loaded from global) -> 4 pk + denom
  auto logits = [&](const float4* cj8, unsigned* pk) {
#pragma unroll
    for (int jp = 0; jp < 4; jp++) {
      const float4 cj0 = cj8[2 * jp];
      const float4 cj1 = cj8[2 * jp + 1];
      float dx0 = cq.x - cj0.x, dy0 = cq.y - cj0.y, dz0 = cq.z - cj0.z;
      float dx1 = cq.x - cj1.x, dy1 = cq.y - cj1.y, dz1 = cq.z - cj1.z;
      float d20 = fmaf(dz0, dz0, fmaf(dy0, dy0, dx0 * dx0));
      float d21 = fmaf(dz1, dz1, fmaf(dy1, dy1, dx1 * dx1));
      float loc0 = ex2(-0.14426950408f * d20);       // = exp(-0.1*d2)
      float loc1 = ex2(-0.14426950408f * d21);
      float xL0 = fsqL + cj0.w, xL1 = fsqL + cj1.w;  // (fsq+fdst)*log2e
      float eL0 = fmaxf(xL0, 0.2f * xL0);            // leaky, scale-invariant
      float eL1 = fmaxf(xL1, 0.2f * xL1);
      float p0 = ex2(fmaf(eL0, loc0, mBqL));         // = exp(e*loc - Bq)
      float p1 = ex2(fmaf(eL1, loc1, mBqL));
      p0 = (d20 < 46.0517f) ? p0 : 0.f;
      p1 = (d21 < 46.0517f) ? p1 : 0.f;
      unsigned r;
      asm("v_cvt_pk_bf16_f32 %0, %1, %2" : "=v"(r) : "v"(p0), "v"(p1));
      pk[jp] = r;
    }
    // denominator: sum the bf16-ROUNDED p's (exactly what the MFMA consumes)
#pragma unroll
    for (int jp = 0; jp < 4; jp++)
      ds += bf2f((unsigned short)(pk[jp] & 0xFFFF)) +
            bf2f((unsigned short)(pk[jp] >> 16));
  };

  auto store_phi = [&](int tt, const unsigned* pk) {
    *(uint4*)&phi[tt & 1][qA][jseg * 8] =
        make_uint4(pk[0], pk[1], pk[2], pk[3]);
  };

  // js-split MFMA (r26 verbatim): wave (fg,js) = 4 q-tiles x 32 f, K-slice js
  auto mfma_tile = [&](int tb) {
    const unsigned short* bb = (const unsigned short*)ldsBu[tb];
    const int f0 = fg * 32 + m;
    const short8 bh0 = *(const short8*)
        &bb[(js * 2 + (quad >> 1)) * 2048 + f0 * 16 + hsel * 8];
    const short8 bh1 = *(const short8*)
        &bb[(js * 2 + (quad >> 1)) * 2048 + (f0 + 16) * 16 + hsel * 8];
#pragma unroll
    for (int qt = 0; qt < 4; qt++) {
      short8 ah = *(const short8*)&phi[tb][qt * 16 + m][js * 32 + quad * 8];
      acc[qt][0] = __builtin_amdgcn_mfma_f32_16x16x32_bf16(ah, bh0, acc[qt][0], 0, 0, 0);
      acc[qt][1] = __builtin_amdgcn_mfma_f32_16x16x32_bf16(ah, bh1, acc[qt][1], 0, 0, 0);
    }
  };

  // ---- prologue: B panel 0 (reg-staged); cj tile 0 from global; logits(0) --
  {
    uint4 pv[2];
#pragma unroll
    for (int k = 0; k < 2; k++) pv[k] = gB[k * 1024 + tid];
#pragma unroll
    for (int k = 0; k < 2; k++) ldsBu[0][k * 1024 + tid] = pv[k];
  }
  {
    float4 cjv[8];
#pragma unroll
    for (int i = 0; i < 8; i++) cjv[i] = cjg[i];
    __syncthreads();                       // ldsB[0] ready
    unsigned pk0[4];
    logits(cjv, pk0);
    store_phi(0, pk0);
  }
  __syncthreads();                         // phi[0] ready

  // ---- main loop: one barrier per 128-j tile ----
  for (int t = 0; t < 16; t++) {
    // 1. issue next-tile loads early (latency hides under MFMA below)
    float4 cjv[8];
    if (t < 15) {
#pragma unroll
      for (int i = 0; i < 8; i++) cjv[i] = cjg[(t + 1) * 128 + i];
    }
    uint4 bv[2];
    if (t < 15) {
#pragma unroll
      for (int k = 0; k < 2; k++)
        bv[k] = gB[(size_t)(t + 1) * 2048 + k * 1024 + tid];
    }

    // 2. MFMA for tile t (LDS + matrix pipes; covers the VMEM latency)
    mfma_tile(t & 1);                      // reads phi[t&1], ldsB[t&1]

    // 3. logits for tile t+1 on register cj
    unsigned pk[4];
    if (t < 15) logits(cjv, pk);

    // 4. publish tile t+1 state (other buffers; prior reads fenced at t-1)
    if (t < 15) {
#pragma unroll
      for (int k = 0; k < 2; k++)
        ldsBu[(t + 1) & 1][k * 1024 + tid] = bv[k];
      store_phi(t + 1, pk);                // -> phi[(t+1)&1]
    }
    __syncthreads();
  }

  // ---- denominator: 16-lane group reduce (threads sharing qA) ----
#pragma unroll
  for (int off = 1; off <= 8; off <<= 1) ds += __shfl_xor(ds, off, 64);
  if (jseg == 0) denomS[qA] = ds;          // read after the merge barriers

  // ---- js-partial acc merge: 2 rounds in the dead ldsB buffer ----
  f32x4* xv = (f32x4*)ldsBu;               // 4096 f32x4 = 64 KB
  auto writeSlot = [&](int slot) {
#pragma unroll
    for (int qt = 0; qt < 4; qt++)
#pragma unroll
      for (int ft = 0; ft < 2; ft++) {
        const int i = qt * 2 + ft;
        xv[slot * 512 + lane * 8 + (i ^ (lane & 7))] = acc[qt][ft];
      }
  };
  auto readSlot = [&](int slot) {
#pragma unroll
    for (int qt = 0; qt < 4; qt++)
#pragma unroll
      for (int ft = 0; ft < 2; ft++) {
        const int i = qt * 2 + ft;
        acc[qt][ft] += xv[slot * 512 + lane * 8 + (i ^ (lane & 7))];
      }
  };
  if (js & 1) writeSlot(fg * 2 + (js >> 1));     // js 1,3 -> slots 0..7
  __syncthreads();
  if (!(js & 1)) readSlot(fg * 2 + (js >> 1));   // js0 += js1; js2 += js3
  __syncthreads();
  if (js == 2) writeSlot(fg);                    // merged js2+3 -> slots 0..3
  __syncthreads();

  // ---- final merge + normalize + elu + store (js==0 waves) ----
  if (js == 0) {
    readSlot(fg);
#pragma unroll
    for (int ft = 0; ft < 2; ft++) {
      const int f = fg * 32 + ft * 16 + m;
#pragma unroll
      for (int qt = 0; qt < 4; qt++)
#pragma unroll
        for (int r = 0; r < 4; r++) {
          const int q = qt * 16 + quad * 4 + r;
          float v = acc[qt][ft][r] / fmaxf(denomS[q], 1e-30f);
          v = (v > 0.f) ? v : (__expf(v) - 1.0f);
          size_t oidx = ((size_t)(b * N_ + q0 + q)) * FOUT_ + f;
          if (isbf) ((unsigned short*)out)[oidx] = f2bf(v);
          else      ((float*)out)[oidx] = v;
        }
    }
  }
}

extern "C" void kernel_launch(void* const* d_in, const int* in_sizes, int n_in,
                              void* d_out, int out_size, void* d_ws, size_t ws_size,
                              hipStream_t stream) {
  const void* x     = d_in[0];
  const void* coord = d_in[1];
  const void* W     = d_in[2];
  const void* a     = d_in[3];

  // ws: [512-float header: flag@0, MdstE @ uint 64 (stride 32)]
  //     [hT][WT][wa][fsrc][cpack]
  int*            flag  = (int*)d_ws;
  unsigned*       MdstE = (unsigned*)d_ws + 64;
  unsigned short* hT    = (unsigned short*)((float*)d_ws + 512);
  unsigned short* WT    = hT + (size_t)NROWS * FOUT_;
  float*          wa    = (float*)(WT + 128 * 256);
  float*          fsrc  = wa + 512;
  float4*         cpack = (float4*)(fsrc + NROWS);   // 16B-aligned offset

  k_prep<<<129, 256, 0, stream>>>(x, W, a, WT, wa, flag, MdstE);
  k_h   <<<NROWS / 32, 256, 0, stream>>>(x, coord, WT, wa, flag, hT, fsrc, cpack, MdstE);
  k_attn<<<B_ * (N_ / 64), 1024, 0, stream>>>(hT, cpack, fsrc, MdstE, flag, d_out);
}

// Round 14
// 135.755 us; speedup vs baseline: 1.3103x; 1.3103x over previous
//
#include <hip/hip_runtime.h>
#include <hip/hip_bf16.h>

#define B_    8
#define N_    2048
#define FIN_  256
#define FOUT_ 128
#define NROWS (B_*N_)

typedef __attribute__((ext_vector_type(8))) short short8;
typedef __attribute__((ext_vector_type(4))) float f32x4;

__device__ __forceinline__ float bf2f(unsigned short u) {
  return __uint_as_float(((unsigned int)u) << 16);
}
__device__ __forceinline__ unsigned short f2bf(float f) {
  unsigned int u = __float_as_uint(f);
  u += 0x7FFFu + ((u >> 16) & 1u);   // RNE
  return (unsigned short)(u >> 16);
}
__device__ __forceinline__ float ldin(const void* p, size_t idx, int isbf) {
  if (isbf) return bf2f(((const unsigned short*)p)[idx]);
  return ((const float*)p)[idx];
}
__device__ __forceinline__ unsigned pk2bf(float a, float b) {
  return (unsigned)f2bf(a) | ((unsigned)f2bf(b) << 16);   // low = a (RNE)
}
// native exp2 (single v_exp_f32); fallback keeps exact same math via e^(x*ln2)
__device__ __forceinline__ float ex2(float x) {
#if __has_builtin(__builtin_amdgcn_exp2f)
  return __builtin_amdgcn_exp2f(x);
#else
  return __expf(x * 0.69314718056f);
#endif
}
// monotone float<->uint encoding for atomicMax float-max (all finite enc > 0)
__device__ __forceinline__ unsigned encf(float f) {
  unsigned u = __float_as_uint(f);
  return (u & 0x80000000u) ? ~u : (u | 0x80000000u);
}
__device__ __forceinline__ float decf(unsigned k) {
  return (k & 0x80000000u) ? __uint_as_float(k ^ 0x80000000u) : __uint_as_float(~k);
}
// per-block dtype self-detect (deterministic across blocks)
__device__ __forceinline__ int detect_bf(const void* x, int* cnt) {
  const unsigned short* u = (const unsigned short*)x;
  int c = 0;
  for (int i = threadIdx.x; i < 8192; i += 256) {
    unsigned short v = u[i];
    int e = (v >> 7) & 0xFF;
    if ((e >= 110 && e <= 145) || (v & 0x7FFF) == 0) c++;
  }
  cnt[threadIdx.x] = c;
  __syncthreads();
  for (int s = 128; s > 0; s >>= 1) {
    if (threadIdx.x < s) cnt[threadIdx.x] += cnt[threadIdx.x + s];
    __syncthreads();
  }
  return cnt[0] > 7373;   // 0.9 * 8192
}

// ---------- kernel 0: self-detect; blocks 0..127: WT; block 128: wa, flag,
//            MdstE init ----------
__global__ __launch_bounds__(256)
void k_prep(const void* __restrict__ x, const void* __restrict__ W,
            const void* __restrict__ a,
            unsigned short* __restrict__ WT, float* __restrict__ wa,
            int* __restrict__ flag, unsigned* __restrict__ MdstE) {
  __shared__ int cnt[256];
  const int isbf = detect_bf(x, cnt);
  if (blockIdx.x < 128) {
    int f = blockIdx.x, k = threadIdx.x;
    WT[f * 256 + k] = f2bf(ldin(W, (size_t)k * 128 + f, isbf));
  } else {
    __shared__ float as_s[256];
    int k = threadIdx.x;
    as_s[k] = ldin(a, k, isbf);
    __syncthreads();
    float s = 0.f, d = 0.f;
    for (int f = 0; f < 128; f++) {
      float w = ldin(W, (size_t)k * 128 + f, isbf);
      s += w * as_s[f];
      d += w * as_s[128 + f];
    }
    wa[k] = s;
    wa[256 + k] = d;
    if (k == 0) *flag = isbf;
    if (k < 8) MdstE[k * 32] = 0u;     // 0 < enc(f) for all finite f
  }
}

// ---------- kernel 1: h = x@W bf16 MFMA -> hT; fused fsrc/fdst = x@wa;
//            fused per-batch fdst max; cpack = (cx,cy,cz, fdst*log2e).
// hT 16B-half XOR swizzle on bit2 of f (phys_half = logical_half ^
// ((f>>2)&1)); k_attn reads with the matching hsel XOR. ----------
__global__ __launch_bounds__(256)
void k_h(const void* __restrict__ x, const void* __restrict__ coord,
         const unsigned short* __restrict__ WT,
         const float* __restrict__ wa, const int* __restrict__ flag,
         unsigned short* __restrict__ hT, float* __restrict__ fsrc,
         float4* __restrict__ cpack, unsigned* __restrict__ MdstE) {
  __shared__ __align__(16) unsigned short xs[32][264];
  __shared__ float wa_s[512];
  __shared__ float mxs[8];
  const int isbf = *flag;
  const int t    = threadIdx.x;
  const int row0 = blockIdx.x * 32;

  wa_s[t] = wa[t];
  wa_s[256 + t] = wa[256 + t];
  __syncthreads();

  const int c = t & 31;
  float sp[4], dp[4];
  if (isbf) {
    const unsigned short* xu = (const unsigned short*)x;
#pragma unroll
    for (int u = 0; u < 4; u++) {
      int r = u * 8 + (t >> 5);
      short8 sh = *(const short8*)&xu[(size_t)(row0 + r) * FIN_ + c * 8];
      *(short8*)&xs[r][c * 8] = sh;
      float s = 0.f, d = 0.f;
#pragma unroll
      for (int e = 0; e < 8; e++) {
        float xv = bf2f((unsigned short)sh[e]);
        s += xv * wa_s[c * 8 + e];
        d += xv * wa_s[256 + c * 8 + e];
      }
      sp[u] = s; dp[u] = d;
    }
  } else {
    const float* xf = (const float*)x;
#pragma unroll
    for (int u = 0; u < 4; u++) {
      int r = u * 8 + (t >> 5);
      float4 v0 = *(const float4*)&xf[(size_t)(row0 + r) * FIN_ + c * 8];
      float4 v1 = *(const float4*)&xf[(size_t)(row0 + r) * FIN_ + c * 8 + 4];
      float vv[8] = {v0.x, v0.y, v0.z, v0.w, v1.x, v1.y, v1.z, v1.w};
      short8 sh;
      float s = 0.f, d = 0.f;
#pragma unroll
      for (int e = 0; e < 8; e++) {
        sh[e] = (short)f2bf(vv[e]);
        s += vv[e] * wa_s[c * 8 + e];
        d += vv[e] * wa_s[256 + c * 8 + e];
      }
      *(short8*)&xs[r][c * 8] = sh;
      sp[u] = s; dp[u] = d;
    }
  }
#pragma unroll
  for (int off = 16; off >= 1; off >>= 1) {
#pragma unroll
    for (int u = 0; u < 4; u++) {
      sp[u] += __shfl_xor(sp[u], off, 64);
      dp[u] += __shfl_xor(dp[u], off, 64);
    }
  }
  if (c == 0) {
    float lm = -1e30f;
#pragma unroll
    for (int u = 0; u < 4; u++) {
      int r = u * 8 + (t >> 5);
      size_t rg = (size_t)(row0 + r);
      fsrc[rg] = sp[u];
      cpack[rg] = make_float4(ldin(coord, rg * 3 + 0, isbf),
                              ldin(coord, rg * 3 + 1, isbf),
                              ldin(coord, rg * 3 + 2, isbf),
                              dp[u] * 1.44269504f);     // fdst pre-scaled by log2e
      lm = fmaxf(lm, dp[u]);
    }
    mxs[t >> 5] = lm;
  }
  __syncthreads();
  if (t == 0) {
    float m8 = mxs[0];
#pragma unroll
    for (int i = 1; i < 8; i++) m8 = fmaxf(m8, mxs[i]);
    atomicMax(&MdstE[(row0 >> 11) * 32], encf(m8));   // 64 atomics/line, padded
  }

  const int lane = t & 63, w = t >> 6;
  const int m = lane & 15, quad = lane >> 4;
  const int slab = w >> 1, fh = w & 1;

  f32x4 acc[4];
#pragma unroll
  for (int i = 0; i < 4; i++) acc[i] = (f32x4){0.f, 0.f, 0.f, 0.f};

#pragma unroll
  for (int ks = 0; ks < 8; ks++) {
    short8 ah = *(const short8*)&xs[slab * 16 + m][ks * 32 + quad * 8];
#pragma unroll
    for (int ft = 0; ft < 4; ft++) {
      int f = fh * 64 + ft * 16 + m;
      short8 bh = *(const short8*)&WT[(size_t)f * 256 + ks * 32 + quad * 8];
      acc[ft] = __builtin_amdgcn_mfma_f32_16x16x32_bf16(ah, bh, acc[ft], 0, 0, 0);
    }
  }

  size_t n0 = (size_t)blockIdx.x * 2 + slab;
  unsigned short* hblk = hT + n0 * (FOUT_ * 16);
#pragma unroll
  for (int ft = 0; ft < 4; ft++) {
    int f = fh * 64 + ft * 16 + m;
    int jo = (quad * 4) ^ (((f >> 2) & 1) << 3);   // bank-swizzled 16B half
    *(uint2*)&hblk[f * 16 + jo] = make_uint2(
        pk2bf(acc[ft][0], acc[ft][1]), pk2bf(acc[ft][2], acc[ft][3]));
  }
}

// ---------- kernel 2 (r31): r26 EXACT (132.6us pass) + two hint-level deltas
// Permlane lever ABANDONED after 3 strikes (r28 asm lo, r29 asm hi, r30
// builtin: 2.02/2.66/2.98) -- no remaining model of the lane routing fits
// all three, and the score sits on r26's pass. Reverted per pre-commitment.
// r31 adds only correctness-neutral-by-construction changes:
//  (1) T5: s_setprio(1..0) around the MFMA cluster (pure scheduler hint;
//      loop has logits-VALU vs MFMA vs staging role diversity).
//  (2) T1: bijective XCD block remap lb=(bid&7)*32+(bid>>3) (256%8==0).
//      Batch = bid&7, so one batch's 32 blocks (sharing its 512KB hT
//      panel) land on one XCD's L2 -> FETCH ~17.5MB -> ~6-8MB.
// Everything else byte-identical to the round-9 passing source.
__global__ __launch_bounds__(1024, 4)
void k_attn(const unsigned short* __restrict__ hT, const float4* __restrict__ cpack,
            const float* __restrict__ fsrc, const unsigned* __restrict__ MdstE,
            const int* __restrict__ flag, void* __restrict__ out) {
  const int isbf = *flag;
  const int tid = threadIdx.x;
  const int lb  = ((int)blockIdx.x & 7) * 32 + ((int)blockIdx.x >> 3);  // T1
  const int b   = lb >> 5;
  const int q0  = (lb & 31) * 64;

  __shared__ __align__(16) uint4 ldsBu[2][2048];            // 64 KB B panels
  __shared__ __align__(16) unsigned short phi[2][64][136];  // 34 KB
  __shared__ __align__(16) float4 cjs[2][144];              // 4.5 KB (padded)
  __shared__ float denomS[64];

  // ---- logit roles (r21/r26 verbatim) ----
  const int qA   = tid >> 4;              // 0..63: logit q row
  const int jseg = tid & 15;              // 8 j's: jseg*8 + 0..7
  const size_t qglb = (size_t)b * N_ + q0 + qA;
  const float4 cq  = cpack[qglb];
  const float  fsq = fsrc[qglb];
  const float  fsqL = fsq * 1.44269504f;
  const float  mBqL = -fmaxf(0.f, fsq + decf(MdstE[b * 32])) * 1.44269504f;
  float ds = 0.f;                         // f32 sum of this thread's bf16 p's

  // ---- mfma roles: 16 waves = 4 fg x 4 js (K-quarter), r26 verbatim ----
  const int lane = tid & 63, w = tid >> 6;
  const int m = lane & 15, quad = lane >> 4;
  const int fg = w & 3, js = w >> 2;
  const int hsel = (quad & 1) ^ ((m >> 2) & 1);   // undo producer swizzle

  f32x4 acc[4][2];                        // [q-tile][f-subtile]
#pragma unroll
  for (int i = 0; i < 4; i++)
#pragma unroll
    for (int j = 0; j < 2; j++) acc[i][j] = (f32x4){0.f, 0.f, 0.f, 0.f};

  const unsigned short* hTb = hT + (size_t)b * (N_ * FOUT_);
  const uint4* gB = (const uint4*)hTb;            // 2048 uint4 per 128-j tile
  const float4* cpb = cpack + (size_t)b * N_;

  // logits for tile tt -> 4 packed bf16 pairs (8 j's) + denom accumulation
  auto logits = [&](int tt, unsigned* pk) {
    const float4* cb = cjs[tt & 1];
#pragma unroll
    for (int jp = 0; jp < 4; jp++) {
      const int j0 = jseg * 8 + 2 * jp;
      const int ix = j0 + (j0 >> 3);
      const float4 cj0 = cb[ix];
      const float4 cj1 = cb[ix + 1];
      float dx0 = cq.x - cj0.x, dy0 = cq.y - cj0.y, dz0 = cq.z - cj0.z;
      float dx1 = cq.x - cj1.x, dy1 = cq.y - cj1.y, dz1 = cq.z - cj1.z;
      float d20 = fmaf(dz0, dz0, fmaf(dy0, dy0, dx0 * dx0));
      float d21 = fmaf(dz1, dz1, fmaf(dy1, dy1, dx1 * dx1));
      float loc0 = ex2(-0.14426950408f * d20);       // = exp(-0.1*d2)
      float loc1 = ex2(-0.14426950408f * d21);
      float xL0 = fsqL + cj0.w, xL1 = fsqL + cj1.w;  // (fsq+fdst)*log2e
      float eL0 = fmaxf(xL0, 0.2f * xL0);            // leaky, scale-invariant
      float eL1 = fmaxf(xL1, 0.2f * xL1);
      float p0 = ex2(fmaf(eL0, loc0, mBqL));         // = exp(e*loc - Bq)
      float p1 = ex2(fmaf(eL1, loc1, mBqL));
      p0 = (d20 < 46.0517f) ? p0 : 0.f;
      p1 = (d21 < 46.0517f) ? p1 : 0.f;
      unsigned r;
      asm("v_cvt_pk_bf16_f32 %0, %1, %2" : "=v"(r) : "v"(p0), "v"(p1));
      pk[jp] = r;
    }
    // denominator: sum the bf16-ROUNDED p's (exactly what the MFMA consumes)
#pragma unroll
    for (int jp = 0; jp < 4; jp++)
      ds += bf2f((unsigned short)(pk[jp] & 0xFFFF)) +
            bf2f((unsigned short)(pk[jp] >> 16));
  };

  auto store_phi = [&](int tt, const unsigned* pk) {
    *(uint4*)&phi[tt & 1][qA][jseg * 8] =
        make_uint4(pk[0], pk[1], pk[2], pk[3]);
  };

  // js-split MFMA: wave (fg, js) covers all 4 q-tiles x 32 f at K-slice js.
  // T5: setprio around the MFMA cluster.
  auto mfma_tile = [&](int tb) {
    const unsigned short* bb = (const unsigned short*)ldsBu[tb];
    const int f0 = fg * 32 + m;
    const short8 bh0 = *(const short8*)
        &bb[(js * 2 + (quad >> 1)) * 2048 + f0 * 16 + hsel * 8];
    const short8 bh1 = *(const short8*)
        &bb[(js * 2 + (quad >> 1)) * 2048 + (f0 + 16) * 16 + hsel * 8];
    __builtin_amdgcn_s_setprio(1);
#pragma unroll
    for (int qt = 0; qt < 4; qt++) {
      short8 ah = *(const short8*)&phi[tb][qt * 16 + m][js * 32 + quad * 8];
      acc[qt][0] = __builtin_amdgcn_mfma_f32_16x16x32_bf16(ah, bh0, acc[qt][0], 0, 0, 0);
      acc[qt][1] = __builtin_amdgcn_mfma_f32_16x16x32_bf16(ah, bh1, acc[qt][1], 0, 0, 0);
    }
    __builtin_amdgcn_s_setprio(0);
  };

  // ---- prologue: coords tiles 0,1; B panel 0 (reg-staged); logits(0) ----
  if (tid < 256) {
    const int tile = tid >> 7, j = tid & 127;
    cjs[tile][j + (j >> 3)] = cpb[tid];
  }
  {
    uint4 pv[2];
#pragma unroll
    for (int k = 0; k < 2; k++) pv[k] = gB[k * 1024 + tid];
#pragma unroll
    for (int k = 0; k < 2; k++) ldsBu[0][k * 1024 + tid] = pv[k];
  }
  __syncthreads();                         // cjs[0,1] + ldsB[0] ready
  {
    unsigned pk0[4];
    logits(0, pk0);
    store_phi(0, pk0);
  }
  __syncthreads();                         // phi[0] ready

  // ---- main loop: one barrier per 128-j tile ----
  const int jr = tid & 127;
  for (int t = 0; t < 16; t++) {
    // 1. issue next-tile loads (latency hides under logits+MFMA below)
    uint4 bv[2];
    if (t < 15) {
#pragma unroll
      for (int k = 0; k < 2; k++)
        bv[k] = gB[(size_t)(t + 1) * 2048 + k * 1024 + tid];
    }
    float4 cg;
    if (t < 14 && tid < 128) cg = cpb[(t + 2) * 128 + jr];

    // 2. logits for tile t+1 (VALU-heavy; overlaps loads + MFMA)
    unsigned pk[4];
    if (t < 15) logits(t + 1, pk);         // reads cjs[(t+1)&1]

    // 3. MFMA for tile t
    mfma_tile(t & 1);                      // reads phi[t&1], ldsB[t&1]

    // 4. publish tile t+1 state (writes go to the OTHER buffers; prior
    //    reads of those buffers were fenced by the barrier at end of t-1)
    if (t < 15) {
#pragma unroll
      for (int k = 0; k < 2; k++)
        ldsBu[(t + 1) & 1][k * 1024 + tid] = bv[k];
      store_phi(t + 1, pk);                // -> phi[(t+1)&1]
    }
    if (t < 14 && tid < 128) cjs[t & 1][jr + (jr >> 3)] = cg;  // tile t+2
    __syncthreads();
  }

  // ---- denominator: 16-lane group reduce (threads sharing qA) ----
#pragma unroll
  for (int off = 1; off <= 8; off <<= 1) ds += __shfl_xor(ds, off, 64);
  if (jseg == 0) denomS[qA] = ds;          // read after the merge barriers

  // ---- js-partial acc merge: 2 rounds in the dead ldsB buffer ----
  f32x4* xv = (f32x4*)ldsBu;               // 4096 f32x4 = 64 KB
  auto writeSlot = [&](int slot) {
#pragma unroll
    for (int qt = 0; qt < 4; qt++)
#pragma unroll
      for (int ft = 0; ft < 2; ft++) {
        const int i = qt * 2 + ft;
        xv[slot * 512 + lane * 8 + (i ^ (lane & 7))] = acc[qt][ft];
      }
  };
  auto readSlot = [&](int slot) {
#pragma unroll
    for (int qt = 0; qt < 4; qt++)
#pragma unroll
      for (int ft = 0; ft < 2; ft++) {
        const int i = qt * 2 + ft;
        acc[qt][ft] += xv[slot * 512 + lane * 8 + (i ^ (lane & 7))];
      }
  };
  if (js & 1) writeSlot(fg * 2 + (js >> 1));     // js 1,3 -> slots 0..7
  __syncthreads();
  if (!(js & 1)) readSlot(fg * 2 + (js >> 1));   // js0 += js1; js2 += js3
  __syncthreads();
  if (js == 2) writeSlot(fg);                    // merged js2+3 -> slots 0..3
  __syncthreads();

  // ---- final merge + normalize + elu + store (js==0 waves) ----
  if (js == 0) {
    readSlot(fg);
#pragma unroll
    for (int ft = 0; ft < 2; ft++) {
      const int f = fg * 32 + ft * 16 + m;
#pragma unroll
      for (int qt = 0; qt < 4; qt++)
#pragma unroll
        for (int r = 0; r < 4; r++) {
          const int q = qt * 16 + quad * 4 + r;
          float v = acc[qt][ft][r] / fmaxf(denomS[q], 1e-30f);
          v = (v > 0.f) ? v : (__expf(v) - 1.0f);
          size_t oidx = ((size_t)(b * N_ + q0 + q)) * FOUT_ + f;
          if (isbf) ((unsigned short*)out)[oidx] = f2bf(v);
          else      ((float*)out)[oidx] = v;
        }
    }
  }
}

extern "C" void kernel_launch(void* const* d_in, const int* in_sizes, int n_in,
                              void* d_out, int out_size, void* d_ws, size_t ws_size,
                              hipStream_t stream) {
  const void* x     = d_in[0];
  const void* coord = d_in[1];
  const void* W     = d_in[2];
  const void* a     = d_in[3];

  // ws: [512-float header: flag@0, MdstE @ uint 64 (stride 32)]
  //     [hT][WT][wa][fsrc][cpack]
  int*            flag  = (int*)d_ws;
  unsigned*       MdstE = (unsigned*)d_ws + 64;
  unsigned short* hT    = (unsigned short*)((float*)d_ws + 512);
  unsigned short* WT    = hT + (size_t)NROWS * FOUT_;
  float*          wa    = (float*)(WT + 128 * 256);
  float*          fsrc  = wa + 512;
  float4*         cpack = (float4*)(fsrc + NROWS);   // 16B-aligned offset

  k_prep<<<129, 256, 0, stream>>>(x, W, a, WT, wa, flag, MdstE);
  k_h   <<<NROWS / 32, 256, 0, stream>>>(x, coord, WT, wa, flag, hT, fsrc, cpack, MdstE);
  k_attn<<<B_ * (N_ / 64), 1024, 0, stream>>>(hT, cpack, fsrc, MdstE, flag, d_out);
}

// Round 15
// 131.585 us; speedup vs baseline: 1.3519x; 1.0317x over previous
//
#include <hip/hip_runtime.h>
#include <hip/hip_bf16.h>

#define B_    8
#define N_    2048
#define FIN_  256
#define FOUT_ 128
#define NROWS (B_*N_)

typedef __attribute__((ext_vector_type(8))) short short8;
typedef __attribute__((ext_vector_type(4))) float f32x4;

__device__ __forceinline__ float bf2f(unsigned short u) {
  return __uint_as_float(((unsigned int)u) << 16);
}
__device__ __forceinline__ unsigned short f2bf(float f) {
  unsigned int u = __float_as_uint(f);
  u += 0x7FFFu + ((u >> 16) & 1u);   // RNE
  return (unsigned short)(u >> 16);
}
__device__ __forceinline__ float ldin(const void* p, size_t idx, int isbf) {
  if (isbf) return bf2f(((const unsigned short*)p)[idx]);
  return ((const float*)p)[idx];
}
__device__ __forceinline__ unsigned pk2bf(float a, float b) {
  return (unsigned)f2bf(a) | ((unsigned)f2bf(b) << 16);   // low = a (RNE)
}
// native exp2 (single v_exp_f32); fallback keeps exact same math via e^(x*ln2)
__device__ __forceinline__ float ex2(float x) {
#if __has_builtin(__builtin_amdgcn_exp2f)
  return __builtin_amdgcn_exp2f(x);
#else
  return __expf(x * 0.69314718056f);
#endif
}
// monotone float<->uint encoding for atomicMax float-max (all finite enc > 0)
__device__ __forceinline__ unsigned encf(float f) {
  unsigned u = __float_as_uint(f);
  return (u & 0x80000000u) ? ~u : (u | 0x80000000u);
}
__device__ __forceinline__ float decf(unsigned k) {
  return (k & 0x80000000u) ? __uint_as_float(k ^ 0x80000000u) : __uint_as_float(~k);
}
// per-block dtype self-detect (deterministic across blocks)
__device__ __forceinline__ int detect_bf(const void* x, int* cnt) {
  const unsigned short* u = (const unsigned short*)x;
  int c = 0;
  for (int i = threadIdx.x; i < 8192; i += 256) {
    unsigned short v = u[i];
    int e = (v >> 7) & 0xFF;
    if ((e >= 110 && e <= 145) || (v & 0x7FFF) == 0) c++;
  }
  cnt[threadIdx.x] = c;
  __syncthreads();
  for (int s = 128; s > 0; s >>= 1) {
    if (threadIdx.x < s) cnt[threadIdx.x] += cnt[threadIdx.x + s];
    __syncthreads();
  }
  return cnt[0] > 7373;   // 0.9 * 8192
}

// ---------- kernel 0: self-detect; blocks 0..127: WT; block 128: wa, flag,
//            MdstE init ----------
__global__ __launch_bounds__(256)
void k_prep(const void* __restrict__ x, const void* __restrict__ W,
            const void* __restrict__ a,
            unsigned short* __restrict__ WT, float* __restrict__ wa,
            int* __restrict__ flag, unsigned* __restrict__ MdstE) {
  __shared__ int cnt[256];
  const int isbf = detect_bf(x, cnt);
  if (blockIdx.x < 128) {
    int f = blockIdx.x, k = threadIdx.x;
    WT[f * 256 + k] = f2bf(ldin(W, (size_t)k * 128 + f, isbf));
  } else {
    __shared__ float as_s[256];
    int k = threadIdx.x;
    as_s[k] = ldin(a, k, isbf);
    __syncthreads();
    float s = 0.f, d = 0.f;
    for (int f = 0; f < 128; f++) {
      float w = ldin(W, (size_t)k * 128 + f, isbf);
      s += w * as_s[f];
      d += w * as_s[128 + f];
    }
    wa[k] = s;
    wa[256 + k] = d;
    if (k == 0) *flag = isbf;
    if (k < 8) MdstE[k * 32] = 0u;     // 0 < enc(f) for all finite f
  }
}

// ---------- kernel 1: h = x@W bf16 MFMA -> hT; fused fsrc/fdst = x@wa;
//            fused per-batch fdst max; cpack = (cx,cy,cz, fdst*log2e).
// hT 16B-half XOR swizzle on bit2 of f (phys_half = logical_half ^
// ((f>>2)&1)); k_attn reads with the matching hsel XOR. ----------
__global__ __launch_bounds__(256)
void k_h(const void* __restrict__ x, const void* __restrict__ coord,
         const unsigned short* __restrict__ WT,
         const float* __restrict__ wa, const int* __restrict__ flag,
         unsigned short* __restrict__ hT, float* __restrict__ fsrc,
         float4* __restrict__ cpack, unsigned* __restrict__ MdstE) {
  __shared__ __align__(16) unsigned short xs[32][264];
  __shared__ float wa_s[512];
  __shared__ float mxs[8];
  const int isbf = *flag;
  const int t    = threadIdx.x;
  const int row0 = blockIdx.x * 32;

  wa_s[t] = wa[t];
  wa_s[256 + t] = wa[256 + t];
  __syncthreads();

  const int c = t & 31;
  float sp[4], dp[4];
  if (isbf) {
    const unsigned short* xu = (const unsigned short*)x;
#pragma unroll
    for (int u = 0; u < 4; u++) {
      int r = u * 8 + (t >> 5);
      short8 sh = *(const short8*)&xu[(size_t)(row0 + r) * FIN_ + c * 8];
      *(short8*)&xs[r][c * 8] = sh;
      float s = 0.f, d = 0.f;
#pragma unroll
      for (int e = 0; e < 8; e++) {
        float xv = bf2f((unsigned short)sh[e]);
        s += xv * wa_s[c * 8 + e];
        d += xv * wa_s[256 + c * 8 + e];
      }
      sp[u] = s; dp[u] = d;
    }
  } else {
    const float* xf = (const float*)x;
#pragma unroll
    for (int u = 0; u < 4; u++) {
      int r = u * 8 + (t >> 5);
      float4 v0 = *(const float4*)&xf[(size_t)(row0 + r) * FIN_ + c * 8];
      float4 v1 = *(const float4*)&xf[(size_t)(row0 + r) * FIN_ + c * 8 + 4];
      float vv[8] = {v0.x, v0.y, v0.z, v0.w, v1.x, v1.y, v1.z, v1.w};
      short8 sh;
      float s = 0.f, d = 0.f;
#pragma unroll
      for (int e = 0; e < 8; e++) {
        sh[e] = (short)f2bf(vv[e]);
        s += vv[e] * wa_s[c * 8 + e];
        d += vv[e] * wa_s[256 + c * 8 + e];
      }
      *(short8*)&xs[r][c * 8] = sh;
      sp[u] = s; dp[u] = d;
    }
  }
#pragma unroll
  for (int off = 16; off >= 1; off >>= 1) {
#pragma unroll
    for (int u = 0; u < 4; u++) {
      sp[u] += __shfl_xor(sp[u], off, 64);
      dp[u] += __shfl_xor(dp[u], off, 64);
    }
  }
  if (c == 0) {
    float lm = -1e30f;
#pragma unroll
    for (int u = 0; u < 4; u++) {
      int r = u * 8 + (t >> 5);
      size_t rg = (size_t)(row0 + r);
      fsrc[rg] = sp[u];
      cpack[rg] = make_float4(ldin(coord, rg * 3 + 0, isbf),
                              ldin(coord, rg * 3 + 1, isbf),
                              ldin(coord, rg * 3 + 2, isbf),
                              dp[u] * 1.44269504f);     // fdst pre-scaled by log2e
      lm = fmaxf(lm, dp[u]);
    }
    mxs[t >> 5] = lm;
  }
  __syncthreads();
  if (t == 0) {
    float m8 = mxs[0];
#pragma unroll
    for (int i = 1; i < 8; i++) m8 = fmaxf(m8, mxs[i]);
    atomicMax(&MdstE[(row0 >> 11) * 32], encf(m8));   // 64 atomics/line, padded
  }

  const int lane = t & 63, w = t >> 6;
  const int m = lane & 15, quad = lane >> 4;
  const int slab = w >> 1, fh = w & 1;

  f32x4 acc[4];
#pragma unroll
  for (int i = 0; i < 4; i++) acc[i] = (f32x4){0.f, 0.f, 0.f, 0.f};

#pragma unroll
  for (int ks = 0; ks < 8; ks++) {
    short8 ah = *(const short8*)&xs[slab * 16 + m][ks * 32 + quad * 8];
#pragma unroll
    for (int ft = 0; ft < 4; ft++) {
      int f = fh * 64 + ft * 16 + m;
      short8 bh = *(const short8*)&WT[(size_t)f * 256 + ks * 32 + quad * 8];
      acc[ft] = __builtin_amdgcn_mfma_f32_16x16x32_bf16(ah, bh, acc[ft], 0, 0, 0);
    }
  }

  size_t n0 = (size_t)blockIdx.x * 2 + slab;
  unsigned short* hblk = hT + n0 * (FOUT_ * 16);
#pragma unroll
  for (int ft = 0; ft < 4; ft++) {
    int f = fh * 64 + ft * 16 + m;
    int jo = (quad * 4) ^ (((f >> 2) & 1) << 3);   // bank-swizzled 16B half
    *(uint2*)&hblk[f * 16 + jo] = make_uint2(
        pk2bf(acc[ft][0], acc[ft][1]), pk2bf(acc[ft][2], acc[ft][3]));
  }
}

// ---------- kernel 2 (r32 = r26 byte-exact, the 132.6us best) -------------
// r31's two "free" hints (T5 setprio, T1 XCD swizzle) came back -3.1us:
// setprio is null-to-negative on barrier-lockstep structures (all 16 waves
// sync per tile -- the m190 GEMM regime, not the m191 attn regime), and the
// XCD swizzle has nothing to recover at 9% HBM. Both reverted.
// Final structure: 64-q blocks, 1024 thr (4 waves/SIMD), reg-staged 32KB
// B panels (double-buffered LDS), one barrier per 128-j tile; js-split
// 16x16x32 MFMA (wave = fg x js covers 4 q-tiles, 2 B-reads/tile);
// register-denominator (bf16-rounded p summed in f32, shuffle-reduced);
// log2-domain logits with v_cvt_pk_bf16_f32 packing; one-time js merge in
// the dead ldsB buffer. k_attn is LDS-issue-bound at ~36us; remaining dur
// is ~88us harness poison-fills + ~6us k_prep/k_h.
__global__ __launch_bounds__(1024, 4)
void k_attn(const unsigned short* __restrict__ hT, const float4* __restrict__ cpack,
            const float* __restrict__ fsrc, const unsigned* __restrict__ MdstE,
            const int* __restrict__ flag, void* __restrict__ out) {
  const int isbf = *flag;
  const int tid = threadIdx.x;
  const int b   = blockIdx.x >> 5;
  const int q0  = (blockIdx.x & 31) * 64;

  __shared__ __align__(16) uint4 ldsBu[2][2048];            // 64 KB B panels
  __shared__ __align__(16) unsigned short phi[2][64][136];  // 34 KB
  __shared__ __align__(16) float4 cjs[2][144];              // 4.5 KB (padded)
  __shared__ float denomS[64];

  // ---- logit roles ----
  const int qA   = tid >> 4;              // 0..63: logit q row
  const int jseg = tid & 15;              // 8 j's: jseg*8 + 0..7
  const size_t qglb = (size_t)b * N_ + q0 + qA;
  const float4 cq  = cpack[qglb];
  const float  fsq = fsrc[qglb];
  const float  fsqL = fsq * 1.44269504f;
  const float  mBqL = -fmaxf(0.f, fsq + decf(MdstE[b * 32])) * 1.44269504f;
  float ds = 0.f;                         // f32 sum of this thread's bf16 p's

  // ---- mfma roles: 16 waves = 4 fg x 4 js (K-quarter) ----
  const int lane = tid & 63, w = tid >> 6;
  const int m = lane & 15, quad = lane >> 4;
  const int fg = w & 3, js = w >> 2;
  const int hsel = (quad & 1) ^ ((m >> 2) & 1);   // undo producer swizzle

  f32x4 acc[4][2];                        // [q-tile][f-subtile]
#pragma unroll
  for (int i = 0; i < 4; i++)
#pragma unroll
    for (int j = 0; j < 2; j++) acc[i][j] = (f32x4){0.f, 0.f, 0.f, 0.f};

  const unsigned short* hTb = hT + (size_t)b * (N_ * FOUT_);
  const uint4* gB = (const uint4*)hTb;            // 2048 uint4 per 128-j tile
  const float4* cpb = cpack + (size_t)b * N_;

  // logits for tile tt -> 4 packed bf16 pairs (8 j's) + denom accumulation
  auto logits = [&](int tt, unsigned* pk) {
    const float4* cb = cjs[tt & 1];
#pragma unroll
    for (int jp = 0; jp < 4; jp++) {
      const int j0 = jseg * 8 + 2 * jp;
      const int ix = j0 + (j0 >> 3);
      const float4 cj0 = cb[ix];
      const float4 cj1 = cb[ix + 1];
      float dx0 = cq.x - cj0.x, dy0 = cq.y - cj0.y, dz0 = cq.z - cj0.z;
      float dx1 = cq.x - cj1.x, dy1 = cq.y - cj1.y, dz1 = cq.z - cj1.z;
      float d20 = fmaf(dz0, dz0, fmaf(dy0, dy0, dx0 * dx0));
      float d21 = fmaf(dz1, dz1, fmaf(dy1, dy1, dx1 * dx1));
      float loc0 = ex2(-0.14426950408f * d20);       // = exp(-0.1*d2)
      float loc1 = ex2(-0.14426950408f * d21);
      float xL0 = fsqL + cj0.w, xL1 = fsqL + cj1.w;  // (fsq+fdst)*log2e
      float eL0 = fmaxf(xL0, 0.2f * xL0);            // leaky, scale-invariant
      float eL1 = fmaxf(xL1, 0.2f * xL1);
      float p0 = ex2(fmaf(eL0, loc0, mBqL));         // = exp(e*loc - Bq)
      float p1 = ex2(fmaf(eL1, loc1, mBqL));
      p0 = (d20 < 46.0517f) ? p0 : 0.f;
      p1 = (d21 < 46.0517f) ? p1 : 0.f;
      unsigned r;
      asm("v_cvt_pk_bf16_f32 %0, %1, %2" : "=v"(r) : "v"(p0), "v"(p1));
      pk[jp] = r;
    }
    // denominator: sum the bf16-ROUNDED p's (exactly what the MFMA consumes)
#pragma unroll
    for (int jp = 0; jp < 4; jp++)
      ds += bf2f((unsigned short)(pk[jp] & 0xFFFF)) +
            bf2f((unsigned short)(pk[jp] >> 16));
  };

  auto store_phi = [&](int tt, const unsigned* pk) {
    *(uint4*)&phi[tt & 1][qA][jseg * 8] =
        make_uint4(pk[0], pk[1], pk[2], pk[3]);
  };

  // js-split MFMA: wave (fg, js) covers all 4 q-tiles x 32 f at K-slice js
  auto mfma_tile = [&](int tb) {
    const unsigned short* bb = (const unsigned short*)ldsBu[tb];
    const int f0 = fg * 32 + m;
    const short8 bh0 = *(const short8*)
        &bb[(js * 2 + (quad >> 1)) * 2048 + f0 * 16 + hsel * 8];
    const short8 bh1 = *(const short8*)
        &bb[(js * 2 + (quad >> 1)) * 2048 + (f0 + 16) * 16 + hsel * 8];
#pragma unroll
    for (int qt = 0; qt < 4; qt++) {
      short8 ah = *(const short8*)&phi[tb][qt * 16 + m][js * 32 + quad * 8];
      acc[qt][0] = __builtin_amdgcn_mfma_f32_16x16x32_bf16(ah, bh0, acc[qt][0], 0, 0, 0);
      acc[qt][1] = __builtin_amdgcn_mfma_f32_16x16x32_bf16(ah, bh1, acc[qt][1], 0, 0, 0);
    }
  };

  // ---- prologue: coords tiles 0,1; B panel 0 (reg-staged); logits(0) ----
  if (tid < 256) {
    const int tile = tid >> 7, j = tid & 127;
    cjs[tile][j + (j >> 3)] = cpb[tid];
  }
  {
    uint4 pv[2];
#pragma unroll
    for (int k = 0; k < 2; k++) pv[k] = gB[k * 1024 + tid];
#pragma unroll
    for (int k = 0; k < 2; k++) ldsBu[0][k * 1024 + tid] = pv[k];
  }
  __syncthreads();                         // cjs[0,1] + ldsB[0] ready
  {
    unsigned pk0[4];
    logits(0, pk0);
    store_phi(0, pk0);
  }
  __syncthreads();                         // phi[0] ready

  // ---- main loop: one barrier per 128-j tile ----
  const int jr = tid & 127;
  for (int t = 0; t < 16; t++) {
    // 1. issue next-tile loads (latency hides under logits+MFMA below)
    uint4 bv[2];
    if (t < 15) {
#pragma unroll
      for (int k = 0; k < 2; k++)
        bv[k] = gB[(size_t)(t + 1) * 2048 + k * 1024 + tid];
    }
    float4 cg;
    if (t < 14 && tid < 128) cg = cpb[(t + 2) * 128 + jr];

    // 2. logits for tile t+1 (VALU-heavy; overlaps loads + MFMA)
    unsigned pk[4];
    if (t < 15) logits(t + 1, pk);         // reads cjs[(t+1)&1]

    // 3. MFMA for tile t
    mfma_tile(t & 1);                      // reads phi[t&1], ldsB[t&1]

    // 4. publish tile t+1 state (writes go to the OTHER buffers; prior
    //    reads of those buffers were fenced by the barrier at end of t-1)
    if (t < 15) {
#pragma unroll
      for (int k = 0; k < 2; k++)
        ldsBu[(t + 1) & 1][k * 1024 + tid] = bv[k];
      store_phi(t + 1, pk);                // -> phi[(t+1)&1]
    }
    if (t < 14 && tid < 128) cjs[t & 1][jr + (jr >> 3)] = cg;  // tile t+2
    __syncthreads();
  }

  // ---- denominator: 16-lane group reduce (threads sharing qA) ----
#pragma unroll
  for (int off = 1; off <= 8; off <<= 1) ds += __shfl_xor(ds, off, 64);
  if (jseg == 0) denomS[qA] = ds;          // read after the merge barriers

  // ---- js-partial acc merge: 2 rounds in the dead ldsB buffer ----
  f32x4* xv = (f32x4*)ldsBu;               // 4096 f32x4 = 64 KB
  auto writeSlot = [&](int slot) {
#pragma unroll
    for (int qt = 0; qt < 4; qt++)
#pragma unroll
      for (int ft = 0; ft < 2; ft++) {
        const int i = qt * 2 + ft;
        xv[slot * 512 + lane * 8 + (i ^ (lane & 7))] = acc[qt][ft];
      }
  };
  auto readSlot = [&](int slot) {
#pragma unroll
    for (int qt = 0; qt < 4; qt++)
#pragma unroll
      for (int ft = 0; ft < 2; ft++) {
        const int i = qt * 2 + ft;
        acc[qt][ft] += xv[slot * 512 + lane * 8 + (i ^ (lane & 7))];
      }
  };
  if (js & 1) writeSlot(fg * 2 + (js >> 1));     // js 1,3 -> slots 0..7
  __syncthreads();
  if (!(js & 1)) readSlot(fg * 2 + (js >> 1));   // js0 += js1; js2 += js3
  __syncthreads();
  if (js == 2) writeSlot(fg);                    // merged js2+3 -> slots 0..3
  __syncthreads();

  // ---- final merge + normalize + elu + store (js==0 waves) ----
  if (js == 0) {
    readSlot(fg);
#pragma unroll
    for (int ft = 0; ft < 2; ft++) {
      const int f = fg * 32 + ft * 16 + m;
#pragma unroll
      for (int qt = 0; qt < 4; qt++)
#pragma unroll
        for (int r = 0; r < 4; r++) {
          const int q = qt * 16 + quad * 4 + r;
          float v = acc[qt][ft][r] / fmaxf(denomS[q], 1e-30f);
          v = (v > 0.f) ? v : (__expf(v) - 1.0f);
          size_t oidx = ((size_t)(b * N_ + q0 + q)) * FOUT_ + f;
          if (isbf) ((unsigned short*)out)[oidx] = f2bf(v);
          else      ((float*)out)[oidx] = v;
        }
    }
  }
}

extern "C" void kernel_launch(void* const* d_in, const int* in_sizes, int n_in,
                              void* d_out, int out_size, void* d_ws, size_t ws_size,
                              hipStream_t stream) {
  const void* x     = d_in[0];
  const void* coord = d_in[1];
  const void* W     = d_in[2];
  const void* a     = d_in[3];

  // ws: [512-float header: flag@0, MdstE @ uint 64 (stride 32)]
  //     [hT][WT][wa][fsrc][cpack]
  int*            flag  = (int*)d_ws;
  unsigned*       MdstE = (unsigned*)d_ws + 64;
  unsigned short* hT    = (unsigned short*)((float*)d_ws + 512);
  unsigned short* WT    = hT + (size_t)NROWS * FOUT_;
  float*          wa    = (float*)(WT + 128 * 256);
  float*          fsrc  = wa + 512;
  float4*         cpack = (float4*)(fsrc + NROWS);   // 16B-aligned offset

  k_prep<<<129, 256, 0, stream>>>(x, W, a, WT, wa, flag, MdstE);
  k_h   <<<NROWS / 32, 256, 0, stream>>>(x, coord, WT, wa, flag, hT, fsrc, cpack, MdstE);
  k_attn<<<B_ * (N_ / 64), 1024, 0, stream>>>(hT, cpack, fsrc, MdstE, flag, d_out);
}